// Round 1
// baseline (5715.731 us; speedup 1.0000x reference)
//
#include <hip/hip_runtime.h>
#include <stdint.h>

typedef unsigned short u16;
typedef unsigned int u32;
typedef __bf16 bf16x8 __attribute__((ext_vector_type(8)));
typedef float f32x4 __attribute__((ext_vector_type(4)));

// problem constants
#define BATCH 8
#define TT    1024
#define DD    1024
#define HH    512
#define GG    2048      // 4*H
#define MR    8192      // B*T rows
#define PTR   1028      // padded rows per batch (2 + 1024 + 2)
#define KCONV 5120      // 5*D
#define LNW   16        // LSTM workgroups per direction

__device__ __forceinline__ float bf2f(u16 u) {
  u32 x = ((u32)u) << 16;
  return __builtin_bit_cast(float, x);
}
__device__ __forceinline__ u16 f2bf(float f) {
  __bf16 b = (__bf16)f;
  return __builtin_bit_cast(u16, b);
}

typedef __attribute__((address_space(1))) const u32 gu32;
typedef __attribute__((address_space(3))) u32 lu32;

// async global->LDS, 16B per lane, wave-uniform LDS base (lane deposits at base+lane*16)
__device__ __forceinline__ void async16(const void* g, void* l) {
  __builtin_amdgcn_global_load_lds((gu32*)(uintptr_t)g,
                                   (lu32*)(u32)(uintptr_t)l, 16, 0, 0);
}

// ---------------- elementwise: f32 -> bf16 ----------------
__global__ void k_f32_to_bf16(const float* __restrict__ in, u16* __restrict__ out, int n4) {
  int i = blockIdx.x * 256 + threadIdx.x;
  if (i >= n4) return;
  float4 v = ((const float4*)in)[i];
  ushort4 o;
  o.x = f2bf(v.x); o.y = f2bf(v.y); o.z = f2bf(v.z); o.w = f2bf(v.w);
  ((ushort4*)out)[i] = o;
}

// ---------------- transpose f32 [R][C] -> bf16 [C][R] ----------------
__global__ void k_transpose(const float* __restrict__ in, u16* __restrict__ out, int R, int C) {
  __shared__ float tile[32][33];
  int bx = blockIdx.x, by = blockIdx.y;
  int tx = threadIdx.x, ty = threadIdx.y;
#pragma unroll
  for (int i = 0; i < 4; ++i)
    tile[ty + i * 8][tx] = in[(size_t)(by * 32 + ty + i * 8) * C + bx * 32 + tx];
  __syncthreads();
#pragma unroll
  for (int i = 0; i < 4; ++i)
    out[(size_t)(bx * 32 + ty + i * 8) * R + by * 32 + tx] = f2bf(tile[tx][ty + i * 8]);
}

// ---------------- bf16 GEMM: C[M][N] = act(A[M][K] @ BT[N][K]^T + bias) ----------------
// 128x128 tile, BK=64, 256 threads = 4 waves (2x2 of 64x64), mfma 16x16x32.
template <int ACT>
__launch_bounds__(256)
__global__ void k_gemm(const u16* __restrict__ A, const u16* __restrict__ BT,
                       const float* __restrict__ bias, u16* __restrict__ C,
                       int M, int N, int K) {
  __shared__ alignas(16) u16 As[128 * 64];
  __shared__ alignas(16) u16 Bs[128 * 64];
  const int tid = threadIdx.x, lane = tid & 63, wv = tid >> 6;
  const int bm = blockIdx.y, bn = blockIdx.x;
  const int wr = (wv >> 1) * 64, wc = (wv & 1) * 64;
  f32x4 acc[4][4] = {};
  const int kcol = (lane & 7) * 8;
  for (int kt = 0; kt < K; kt += 64) {
#pragma unroll
    for (int c = 0; c < 4; ++c) {
      int chunk = wv * 4 + c;
      int row = chunk * 8 + (lane >> 3);
      async16(A + (size_t)(bm * 128 + row) * K + kt + kcol, (char*)As + chunk * 1024);
      async16(BT + (size_t)(bn * 128 + row) * K + kt + kcol, (char*)Bs + chunk * 1024);
    }
    __syncthreads();
#pragma unroll
    for (int kk = 0; kk < 2; ++kk) {
      bf16x8 af[4], bf[4];
#pragma unroll
      for (int m = 0; m < 4; ++m)
        af[m] = *(const bf16x8*)((const char*)As + ((wr + m * 16 + (lane & 15)) * 64 + kk * 32 + (lane >> 4) * 8) * 2);
#pragma unroll
      for (int n = 0; n < 4; ++n)
        bf[n] = *(const bf16x8*)((const char*)Bs + ((wc + n * 16 + (lane & 15)) * 64 + kk * 32 + (lane >> 4) * 8) * 2);
#pragma unroll
      for (int m = 0; m < 4; ++m)
#pragma unroll
        for (int n = 0; n < 4; ++n)
          acc[m][n] = __builtin_amdgcn_mfma_f32_16x16x32_bf16(af[m], bf[n], acc[m][n], 0, 0, 0);
    }
    __syncthreads();
  }
#pragma unroll
  for (int n = 0; n < 4; ++n) {
    int col = bn * 128 + wc + n * 16 + (lane & 15);
    float bv = bias[col];
#pragma unroll
    for (int m = 0; m < 4; ++m)
#pragma unroll
      for (int j = 0; j < 4; ++j) {
        int row = bm * 128 + wr + m * 16 + (lane >> 4) * 4 + j;
        float v = acc[m][n][j] + bv;
        if (ACT) v = fmaxf(v, 0.f);
        C[(size_t)row * N + col] = f2bf(v);
      }
  }
}

// ---------------- conv1d-as-GEMM: Cf[8192][1024] = Ap(pad) (*) ckT + bias ----------------
// Ap: padded activations [8][1028][1024] bf16. ckT: [co=1024][5120] bf16. K tile 64 within one tap w.
__launch_bounds__(256)
__global__ void k_conv_gemm(const u16* __restrict__ Ap, const u16* __restrict__ BT,
                            const float* __restrict__ bias, float* __restrict__ Cf) {
  __shared__ alignas(16) u16 As[128 * 64];
  __shared__ alignas(16) u16 Bs[128 * 64];
  const int tid = threadIdx.x, lane = tid & 63, wv = tid >> 6;
  const int bm = blockIdx.y, bn = blockIdx.x;
  const int b = (bm * 128) >> 10;
  const int t0 = (bm * 128) & 1023;
  const int wr = (wv >> 1) * 64, wc = (wv & 1) * 64;
  f32x4 acc[4][4] = {};
  const int kcol = (lane & 7) * 8;
  for (int kt = 0; kt < KCONV; kt += 64) {
    int w = kt >> 10, ci0 = kt & 1023;
#pragma unroll
    for (int c = 0; c < 4; ++c) {
      int chunk = wv * 4 + c;
      int row = chunk * 8 + (lane >> 3);
      async16(Ap + ((size_t)(b * PTR + t0 + row + w)) * 1024 + ci0 + kcol, (char*)As + chunk * 1024);
      async16(BT + (size_t)(bn * 128 + row) * KCONV + kt + kcol, (char*)Bs + chunk * 1024);
    }
    __syncthreads();
#pragma unroll
    for (int kk = 0; kk < 2; ++kk) {
      bf16x8 af[4], bf[4];
#pragma unroll
      for (int m = 0; m < 4; ++m)
        af[m] = *(const bf16x8*)((const char*)As + ((wr + m * 16 + (lane & 15)) * 64 + kk * 32 + (lane >> 4) * 8) * 2);
#pragma unroll
      for (int n = 0; n < 4; ++n)
        bf[n] = *(const bf16x8*)((const char*)Bs + ((wc + n * 16 + (lane & 15)) * 64 + kk * 32 + (lane >> 4) * 8) * 2);
#pragma unroll
      for (int m = 0; m < 4; ++m)
#pragma unroll
        for (int n = 0; n < 4; ++n)
          acc[m][n] = __builtin_amdgcn_mfma_f32_16x16x32_bf16(af[m], bf[n], acc[m][n], 0, 0, 0);
    }
    __syncthreads();
  }
#pragma unroll
  for (int n = 0; n < 4; ++n) {
    int col = bn * 128 + wc + n * 16 + (lane & 15);
    float bv = bias[col];
#pragma unroll
    for (int m = 0; m < 4; ++m)
#pragma unroll
      for (int j = 0; j < 4; ++j) {
        int row = bm * 128 + wr + m * 16 + (lane >> 4) * 4 + j;
        Cf[(size_t)row * 1024 + col] = acc[m][n][j] + bv;
      }
  }
}

// ---------------- BN stats (deterministic two-stage) ----------------
__global__ void k_bnstats1(const float* __restrict__ x, float* __restrict__ part) {
  int blk = blockIdx.x;          // 64 blocks, 128 rows each
  int t = threadIdx.x;           // 256 threads, 4 channels each
  float4 s = {0, 0, 0, 0}, q = {0, 0, 0, 0};
  for (int r = blk * 128; r < blk * 128 + 128; ++r) {
    float4 v = ((const float4*)x)[(size_t)r * 256 + t];
    s.x += v.x; s.y += v.y; s.z += v.z; s.w += v.w;
    q.x += v.x * v.x; q.y += v.y * v.y; q.z += v.z * v.z; q.w += v.w * v.w;
  }
  int c0 = t * 4;
  size_t base = ((size_t)blk * 1024 + c0) * 2;
  part[base + 0] = s.x; part[base + 1] = q.x;
  part[base + 2] = s.y; part[base + 3] = q.y;
  part[base + 4] = s.z; part[base + 5] = q.z;
  part[base + 6] = s.w; part[base + 7] = q.w;
}

__global__ void k_bnstats2(const float* __restrict__ part, const float* __restrict__ gw,
                           const float* __restrict__ bw, float* __restrict__ scale,
                           float* __restrict__ shift) {
  int c = blockIdx.x * 256 + threadIdx.x;
  float s = 0.f, q = 0.f;
  for (int i = 0; i < 64; ++i) {
    s += part[((size_t)i * 1024 + c) * 2 + 0];
    q += part[((size_t)i * 1024 + c) * 2 + 1];
  }
  float mu = s / 8192.f;
  float var = q / 8192.f - mu * mu;
  float sc = rsqrtf(var + 1e-5f) * gw[c];
  scale[c] = sc;
  shift[c] = bw[c] - mu * sc;
}

// BN apply + tanh, writes padded bf16 activations (pad rows -> 0)
__global__ void k_bn_tanh(const float* __restrict__ conv, const float* __restrict__ scale,
                          const float* __restrict__ shift, u16* __restrict__ outp) {
  int i = blockIdx.x * 256 + threadIdx.x;  // vec4 index over 8*1028*1024/4
  int c4 = i & 255;
  int prow = i >> 8;
  int b = prow / PTR, pt = prow % PTR;
  ushort4 o;
  if (pt < 2 || pt >= 1026) {
    o.x = 0; o.y = 0; o.z = 0; o.w = 0;
  } else {
    float4 v = ((const float4*)conv)[((size_t)(b * 1024 + pt - 2) << 8) + c4];
    int c = c4 * 4;
    o.x = f2bf(tanhf(v.x * scale[c + 0] + shift[c + 0]));
    o.y = f2bf(tanhf(v.y * scale[c + 1] + shift[c + 1]));
    o.z = f2bf(tanhf(v.z * scale[c + 2] + shift[c + 2]));
    o.w = f2bf(tanhf(v.w * scale[c + 3] + shift[c + 3]));
  }
  ((ushort4*)outp)[i] = o;
}

// zero the 4 pad rows per batch of p_concat
__global__ void k_zero_pads(u16* __restrict__ pcat) {
  int i = blockIdx.x * 256 + threadIdx.x;  // 0..32767
  int c = i & 1023;
  int r = i >> 10;               // 32 pad rows total
  int b = r >> 2, q = r & 3;
  int pt = (q < 2) ? q : (1024 + q);
  pcat[((size_t)(b * PTR + pt) << 10) + c] = 0;
}

// ---------------- BiLSTM scan ----------------
// 32 WGs (16/dir) x 256 thr (4 waves). Each WG owns 128 gate cols (wave wv = gate wv, jj 0..31),
// wh b-fragments persistent in registers. h exchanged via agent-scope atomics (packed 2xbf16).
__launch_bounds__(256)
__global__ void k_lstm(const u16* __restrict__ xgf, const u16* __restrict__ xgb,
                       const u16* __restrict__ whfT, const u16* __restrict__ whbT,
                       u16* __restrict__ pcat, u32* done, u32* hbuf) {
  const int wg = blockIdx.x, dir = wg >> 4, w = wg & 15;
  const u16* xg = dir ? xgb : xgf;
  const u16* whT = dir ? whbT : whfT;
  __shared__ alignas(16) u16 h_sl[16 * 512];  // XOR-swizzled rows, rows 8..15 stay zero
  __shared__ float g_sl[8 * 128];
  __shared__ float c_sl[256];
  const int tid = threadIdx.x, lane = tid & 63, wv = tid >> 6;

  // persistent wh B-fragments: wave wv covers LDS-cols [wv*32, wv*32+32) = gate wv, jj 0..31
  bf16x8 breg[2][16];
#pragma unroll
  for (int ct = 0; ct < 2; ++ct) {
    int br = wv * 32 + ct * 16 + (lane & 15);
    int gr = (br >> 5) * 512 + w * 32 + (br & 31);   // global whT row (gate*512 + col)
#pragma unroll
    for (int kk = 0; kk < 16; ++kk) {
      int k = kk * 32 + (lane >> 4) * 8;
      breg[ct][kk] = *(const bf16x8*)(whT + (size_t)gr * 512 + k);
    }
  }
  for (int i = tid; i < 4096; i += 256) ((u32*)h_sl)[i] = 0;
  c_sl[tid] = 0.f;
  __syncthreads();

  for (int s = 0; s < 1024; ++s) {
    const int t = dir ? (1023 - s) : s;
    if (s > 0) {
      if (tid == 0) {
        while (__hip_atomic_load(&done[dir * 1024 + s - 1], __ATOMIC_ACQUIRE,
                                 __HIP_MEMORY_SCOPE_AGENT) < LNW)
          __builtin_amdgcn_s_sleep(1);
      }
      __syncthreads();
      const u32* hb = hbuf + ((dir << 1) | ((s - 1) & 1)) * 2048;
#pragma unroll
      for (int i = 0; i < 8; ++i) {
        int idx = tid + 256 * i;
        u32 v = __hip_atomic_load(&hb[idx], __ATOMIC_RELAXED, __HIP_MEMORY_SCOPE_AGENT);
        int r = idx >> 8, cb = (idx & 255) << 2;
        *(u32*)((char*)h_sl + r * 1024 + (cb ^ ((r & 7) << 4))) = v;
      }
      __syncthreads();
    }
    // recurrent GEMM: g_part[16 x 128] = h[16 x 512] @ wh_slice
    f32x4 acc0 = {0, 0, 0, 0}, acc1 = {0, 0, 0, 0};
#pragma unroll
    for (int kk = 0; kk < 16; ++kk) {
      int ar = lane & 15;
      int kbyte = kk * 64 + (lane >> 4) * 16;
      bf16x8 a = *(const bf16x8*)((const char*)h_sl + ar * 1024 + (kbyte ^ ((ar & 7) << 4)));
      acc0 = __builtin_amdgcn_mfma_f32_16x16x32_bf16(a, breg[0][kk], acc0, 0, 0, 0);
      acc1 = __builtin_amdgcn_mfma_f32_16x16x32_bf16(a, breg[1][kk], acc1, 0, 0, 0);
    }
#pragma unroll
    for (int j = 0; j < 4; ++j) {
      int row = (lane >> 4) * 4 + j;
      if (row < 8) {
        g_sl[row * 128 + wv * 32 + (lane & 15)] = acc0[j];
        g_sl[row * 128 + wv * 32 + 16 + (lane & 15)] = acc1[j];
      }
    }
    __syncthreads();
    // gates: thread = (b, jj)
    {
      const int b = tid >> 5, jj = tid & 31;
      const size_t xrow = ((size_t)(b * 1024 + t)) * 2048 + w * 32 + jj;
      float gi = bf2f(xg[xrow]) + g_sl[b * 128 + jj];
      float gf = bf2f(xg[xrow + 512]) + g_sl[b * 128 + 32 + jj];
      float gg = bf2f(xg[xrow + 1024]) + g_sl[b * 128 + 64 + jj];
      float go = bf2f(xg[xrow + 1536]) + g_sl[b * 128 + 96 + jj];
      float si = 1.f / (1.f + __expf(-gi));
      float sf = 1.f / (1.f + __expf(-gf));
      float so = 1.f / (1.f + __expf(-go));
      float cc = sf * c_sl[tid] + si * tanhf(gg);
      c_sl[tid] = cc;
      float hh = so * tanhf(cc);
      u16 hbits = f2bf(hh);
      pcat[((size_t)(b * PTR + t + 2) << 10) + dir * 512 + w * 32 + jj] = hbits;
      int other = __shfl_down((int)hbits, 1);
      if (!(jj & 1)) {
        u32 val = (u32)hbits | ((u32)(other & 0xffff) << 16);
        u32* hbo = hbuf + ((dir << 1) | (s & 1)) * 2048;
        __hip_atomic_store(&hbo[b * 256 + w * 16 + (jj >> 1)], val, __ATOMIC_RELAXED,
                           __HIP_MEMORY_SCOPE_AGENT);
      }
    }
    __syncthreads();
    if (tid == 0)
      __hip_atomic_fetch_add(&done[dir * 1024 + s], 1u, __ATOMIC_RELEASE,
                             __HIP_MEMORY_SCOPE_AGENT);
  }
}

// ---------------- host ----------------
extern "C" void kernel_launch(void* const* d_in, const int* in_sizes, int n_in,
                              void* d_out, int out_size, void* d_ws, size_t ws_size,
                              hipStream_t stream) {
  const float* x    = (const float*)d_in[0];
  const float* w1   = (const float*)d_in[1];
  const float* b1   = (const float*)d_in[2];
  const float* w2   = (const float*)d_in[3];
  const float* b2   = (const float*)d_in[4];
  const float* wx_f = (const float*)d_in[5];
  const float* wh_f = (const float*)d_in[6];
  const float* bl_f = (const float*)d_in[7];
  const float* wx_b = (const float*)d_in[8];
  const float* wh_b = (const float*)d_in[9];
  const float* bl_b = (const float*)d_in[10];
  const float* ck1  = (const float*)d_in[11];
  const float* cb1  = (const float*)d_in[12];
  const float* g1   = (const float*)d_in[13];
  const float* be1  = (const float*)d_in[14];
  const float* ck2  = (const float*)d_in[15];
  const float* cb2  = (const float*)d_in[16];
  const float* g2   = (const float*)d_in[17];
  const float* be2  = (const float*)d_in[18];
  const float* ck3  = (const float*)d_in[19];
  const float* cb3  = (const float*)d_in[20];
  float* out = (float*)d_out;

  char* ws = (char*)d_ws;
  size_t off = 0;
  auto alloc = [&](size_t n) { size_t o = off; off += (n + 255) & ~(size_t)255; return o; };
  u16* w1T  = (u16*)(ws + alloc((size_t)1024 * 1024 * 2));
  u16* w2T  = (u16*)(ws + alloc((size_t)1024 * 1024 * 2));
  u16* wxfT = (u16*)(ws + alloc((size_t)2048 * 1024 * 2));
  u16* wxbT = (u16*)(ws + alloc((size_t)2048 * 1024 * 2));
  u16* whfT = (u16*)(ws + alloc((size_t)2048 * 512 * 2));
  u16* whbT = (u16*)(ws + alloc((size_t)2048 * 512 * 2));
  u16* ck1T = (u16*)(ws + alloc((size_t)1024 * KCONV * 2));
  u16* ck2T = (u16*)(ws + alloc((size_t)1024 * KCONV * 2));
  u16* ck3T = (u16*)(ws + alloc((size_t)1024 * KCONV * 2));
  u16* xb   = (u16*)(ws + alloc((size_t)MR * 1024 * 2));
  u16* h1   = (u16*)(ws + alloc((size_t)MR * 1024 * 2));
  u16* hm   = (u16*)(ws + alloc((size_t)MR * 1024 * 2));
  u16* xgf  = (u16*)(ws + alloc((size_t)MR * 2048 * 2));
  u16* xgb  = (u16*)(ws + alloc((size_t)MR * 2048 * 2));
  u16* pcat = (u16*)(ws + alloc((size_t)BATCH * PTR * 1024 * 2));
  u16* pa1  = (u16*)(ws + alloc((size_t)BATCH * PTR * 1024 * 2));
  u16* pa2  = (u16*)(ws + alloc((size_t)BATCH * PTR * 1024 * 2));
  u32* hbuf = (u32*)(ws + alloc((size_t)2 * 2 * 2048 * 4));
  u32* done = (u32*)(ws + alloc((size_t)2 * 1024 * 4));
  float* part  = (float*)(ws + alloc((size_t)64 * 1024 * 2 * 4));
  float* scale = (float*)(ws + alloc((size_t)1024 * 4));
  float* shift = (float*)(ws + alloc((size_t)1024 * 4));
  (void)ws_size; (void)in_sizes; (void)n_in; (void)out_size;

  dim3 tb(32, 8);
  // weight transposes + bf16 conversion
  k_transpose<<<dim3(32, 32), tb, 0, stream>>>(w1, w1T, 1024, 1024);
  k_transpose<<<dim3(32, 32), tb, 0, stream>>>(w2, w2T, 1024, 1024);
  k_transpose<<<dim3(64, 32), tb, 0, stream>>>(wx_f, wxfT, 1024, 2048);
  k_transpose<<<dim3(64, 32), tb, 0, stream>>>(wx_b, wxbT, 1024, 2048);
  k_transpose<<<dim3(64, 16), tb, 0, stream>>>(wh_f, whfT, 512, 2048);
  k_transpose<<<dim3(64, 16), tb, 0, stream>>>(wh_b, whbT, 512, 2048);
  k_transpose<<<dim3(32, 160), tb, 0, stream>>>(ck1, ck1T, KCONV, 1024);
  k_transpose<<<dim3(32, 160), tb, 0, stream>>>(ck2, ck2T, KCONV, 1024);
  k_transpose<<<dim3(32, 160), tb, 0, stream>>>(ck3, ck3T, KCONV, 1024);
  k_f32_to_bf16<<<8192, 256, 0, stream>>>(x, xb, MR * 1024 / 4);

  // MLP
  k_gemm<1><<<dim3(8, 64), 256, 0, stream>>>(xb, w1T, b1, h1, MR, 1024, 1024);
  k_gemm<0><<<dim3(8, 64), 256, 0, stream>>>(h1, w2T, b2, hm, MR, 1024, 1024);
  // LSTM input projections (bias folded in)
  k_gemm<0><<<dim3(16, 64), 256, 0, stream>>>(hm, wxfT, bl_f, xgf, MR, 2048, 1024);
  k_gemm<0><<<dim3(16, 64), 256, 0, stream>>>(hm, wxbT, bl_b, xgb, MR, 2048, 1024);

  // LSTM scan
  hipMemsetAsync(done, 0, (size_t)2 * 1024 * 4, stream);
  k_zero_pads<<<128, 256, 0, stream>>>(pcat);
  k_lstm<<<32, 256, 0, stream>>>(xgf, xgb, whfT, whbT, pcat, done, hbuf);

  // conv1 + BN + tanh
  k_conv_gemm<<<dim3(8, 64), 256, 0, stream>>>(pcat, ck1T, cb1, out);
  k_bnstats1<<<64, 256, 0, stream>>>(out, part);
  k_bnstats2<<<4, 256, 0, stream>>>(part, g1, be1, scale, shift);
  k_bn_tanh<<<8224, 256, 0, stream>>>(out, scale, shift, pa1);
  // conv2 + BN + tanh
  k_conv_gemm<<<dim3(8, 64), 256, 0, stream>>>(pa1, ck2T, cb2, out);
  k_bnstats1<<<64, 256, 0, stream>>>(out, part);
  k_bnstats2<<<4, 256, 0, stream>>>(part, g2, be2, scale, shift);
  k_bn_tanh<<<8224, 256, 0, stream>>>(out, scale, shift, pa2);
  // conv3 (final, fp32 out)
  k_conv_gemm<<<dim3(8, 64), 256, 0, stream>>>(pa2, ck3T, cb3, out);
}

// Round 2
// 3899.834 us; speedup vs baseline: 1.4656x; 1.4656x over previous
//
#include <hip/hip_runtime.h>
#include <stdint.h>

typedef unsigned short u16;
typedef unsigned int u32;
typedef unsigned long long u64;
typedef __bf16 bf16x8 __attribute__((ext_vector_type(8)));
typedef float f32x4 __attribute__((ext_vector_type(4)));

// problem constants
#define BATCH 8
#define TT    1024
#define DD    1024
#define HH    512
#define GG    2048      // 4*H
#define MR    8192      // B*T rows
#define PTR   1028      // padded rows per batch (2 + 1024 + 2)
#define KCONV 5120      // 5*D
#define LNW   16        // LSTM workgroups per direction

__device__ __forceinline__ float bf2f(u16 u) {
  u32 x = ((u32)u) << 16;
  return __builtin_bit_cast(float, x);
}
__device__ __forceinline__ u16 f2bf(float f) {
  __bf16 b = (__bf16)f;
  return __builtin_bit_cast(u16, b);
}

typedef __attribute__((address_space(1))) const u32 gu32;
typedef __attribute__((address_space(3))) u32 lu32;

// async global->LDS, 16B per lane, wave-uniform LDS base (lane deposits at base+lane*16)
__device__ __forceinline__ void async16(const void* g, void* l) {
  __builtin_amdgcn_global_load_lds((gu32*)(uintptr_t)g,
                                   (lu32*)(u32)(uintptr_t)l, 16, 0, 0);
}

// ---------------- elementwise: f32 -> bf16 ----------------
__global__ void k_f32_to_bf16(const float* __restrict__ in, u16* __restrict__ out, int n4) {
  int i = blockIdx.x * 256 + threadIdx.x;
  if (i >= n4) return;
  float4 v = ((const float4*)in)[i];
  ushort4 o;
  o.x = f2bf(v.x); o.y = f2bf(v.y); o.z = f2bf(v.z); o.w = f2bf(v.w);
  ((ushort4*)out)[i] = o;
}

// ---------------- transpose f32 [R][C] -> bf16 [C][R] ----------------
__global__ void k_transpose(const float* __restrict__ in, u16* __restrict__ out, int R, int C) {
  __shared__ float tile[32][33];
  int bx = blockIdx.x, by = blockIdx.y;
  int tx = threadIdx.x, ty = threadIdx.y;
#pragma unroll
  for (int i = 0; i < 4; ++i)
    tile[ty + i * 8][tx] = in[(size_t)(by * 32 + ty + i * 8) * C + bx * 32 + tx];
  __syncthreads();
#pragma unroll
  for (int i = 0; i < 4; ++i)
    out[(size_t)(bx * 32 + ty + i * 8) * R + by * 32 + tx] = f2bf(tile[tx][ty + i * 8]);
}

// ---------------- bf16 GEMM: C[M][N] = act(A[M][K] @ BT[N][K]^T + bias) ----------------
template <int ACT>
__launch_bounds__(256)
__global__ void k_gemm(const u16* __restrict__ A, const u16* __restrict__ BT,
                       const float* __restrict__ bias, u16* __restrict__ C,
                       int M, int N, int K) {
  __shared__ alignas(16) u16 As[128 * 64];
  __shared__ alignas(16) u16 Bs[128 * 64];
  const int tid = threadIdx.x, lane = tid & 63, wv = tid >> 6;
  const int bm = blockIdx.y, bn = blockIdx.x;
  const int wr = (wv >> 1) * 64, wc = (wv & 1) * 64;
  f32x4 acc[4][4] = {};
  const int kcol = (lane & 7) * 8;
  for (int kt = 0; kt < K; kt += 64) {
#pragma unroll
    for (int c = 0; c < 4; ++c) {
      int chunk = wv * 4 + c;
      int row = chunk * 8 + (lane >> 3);
      async16(A + (size_t)(bm * 128 + row) * K + kt + kcol, (char*)As + chunk * 1024);
      async16(BT + (size_t)(bn * 128 + row) * K + kt + kcol, (char*)Bs + chunk * 1024);
    }
    __syncthreads();
#pragma unroll
    for (int kk = 0; kk < 2; ++kk) {
      bf16x8 af[4], bf[4];
#pragma unroll
      for (int m = 0; m < 4; ++m)
        af[m] = *(const bf16x8*)((const char*)As + ((wr + m * 16 + (lane & 15)) * 64 + kk * 32 + (lane >> 4) * 8) * 2);
#pragma unroll
      for (int n = 0; n < 4; ++n)
        bf[n] = *(const bf16x8*)((const char*)Bs + ((wc + n * 16 + (lane & 15)) * 64 + kk * 32 + (lane >> 4) * 8) * 2);
#pragma unroll
      for (int m = 0; m < 4; ++m)
#pragma unroll
        for (int n = 0; n < 4; ++n)
          acc[m][n] = __builtin_amdgcn_mfma_f32_16x16x32_bf16(af[m], bf[n], acc[m][n], 0, 0, 0);
    }
    __syncthreads();
  }
#pragma unroll
  for (int n = 0; n < 4; ++n) {
    int col = bn * 128 + wc + n * 16 + (lane & 15);
    float bv = bias[col];
#pragma unroll
    for (int m = 0; m < 4; ++m)
#pragma unroll
      for (int j = 0; j < 4; ++j) {
        int row = bm * 128 + wr + m * 16 + (lane >> 4) * 4 + j;
        float v = acc[m][n][j] + bv;
        if (ACT) v = fmaxf(v, 0.f);
        C[(size_t)row * N + col] = f2bf(v);
      }
  }
}

// ---------------- conv1d-as-GEMM ----------------
__launch_bounds__(256)
__global__ void k_conv_gemm(const u16* __restrict__ Ap, const u16* __restrict__ BT,
                            const float* __restrict__ bias, float* __restrict__ Cf) {
  __shared__ alignas(16) u16 As[128 * 64];
  __shared__ alignas(16) u16 Bs[128 * 64];
  const int tid = threadIdx.x, lane = tid & 63, wv = tid >> 6;
  const int bm = blockIdx.y, bn = blockIdx.x;
  const int b = (bm * 128) >> 10;
  const int t0 = (bm * 128) & 1023;
  const int wr = (wv >> 1) * 64, wc = (wv & 1) * 64;
  f32x4 acc[4][4] = {};
  const int kcol = (lane & 7) * 8;
  for (int kt = 0; kt < KCONV; kt += 64) {
    int w = kt >> 10, ci0 = kt & 1023;
#pragma unroll
    for (int c = 0; c < 4; ++c) {
      int chunk = wv * 4 + c;
      int row = chunk * 8 + (lane >> 3);
      async16(Ap + ((size_t)(b * PTR + t0 + row + w)) * 1024 + ci0 + kcol, (char*)As + chunk * 1024);
      async16(BT + (size_t)(bn * 128 + row) * KCONV + kt + kcol, (char*)Bs + chunk * 1024);
    }
    __syncthreads();
#pragma unroll
    for (int kk = 0; kk < 2; ++kk) {
      bf16x8 af[4], bf[4];
#pragma unroll
      for (int m = 0; m < 4; ++m)
        af[m] = *(const bf16x8*)((const char*)As + ((wr + m * 16 + (lane & 15)) * 64 + kk * 32 + (lane >> 4) * 8) * 2);
#pragma unroll
      for (int n = 0; n < 4; ++n)
        bf[n] = *(const bf16x8*)((const char*)Bs + ((wc + n * 16 + (lane & 15)) * 64 + kk * 32 + (lane >> 4) * 8) * 2);
#pragma unroll
      for (int m = 0; m < 4; ++m)
#pragma unroll
        for (int n = 0; n < 4; ++n)
          acc[m][n] = __builtin_amdgcn_mfma_f32_16x16x32_bf16(af[m], bf[n], acc[m][n], 0, 0, 0);
    }
    __syncthreads();
  }
#pragma unroll
  for (int n = 0; n < 4; ++n) {
    int col = bn * 128 + wc + n * 16 + (lane & 15);
    float bv = bias[col];
#pragma unroll
    for (int m = 0; m < 4; ++m)
#pragma unroll
      for (int j = 0; j < 4; ++j) {
        int row = bm * 128 + wr + m * 16 + (lane >> 4) * 4 + j;
        Cf[(size_t)row * 1024 + col] = acc[m][n][j] + bv;
      }
  }
}

// ---------------- BN stats (deterministic two-stage) ----------------
__global__ void k_bnstats1(const float* __restrict__ x, float* __restrict__ part) {
  int blk = blockIdx.x;
  int t = threadIdx.x;
  float4 s = {0, 0, 0, 0}, q = {0, 0, 0, 0};
  for (int r = blk * 128; r < blk * 128 + 128; ++r) {
    float4 v = ((const float4*)x)[(size_t)r * 256 + t];
    s.x += v.x; s.y += v.y; s.z += v.z; s.w += v.w;
    q.x += v.x * v.x; q.y += v.y * v.y; q.z += v.z * v.z; q.w += v.w * v.w;
  }
  int c0 = t * 4;
  size_t base = ((size_t)blk * 1024 + c0) * 2;
  part[base + 0] = s.x; part[base + 1] = q.x;
  part[base + 2] = s.y; part[base + 3] = q.y;
  part[base + 4] = s.z; part[base + 5] = q.z;
  part[base + 6] = s.w; part[base + 7] = q.w;
}

__global__ void k_bnstats2(const float* __restrict__ part, const float* __restrict__ gw,
                           const float* __restrict__ bw, float* __restrict__ scale,
                           float* __restrict__ shift) {
  int c = blockIdx.x * 256 + threadIdx.x;
  float s = 0.f, q = 0.f;
  for (int i = 0; i < 64; ++i) {
    s += part[((size_t)i * 1024 + c) * 2 + 0];
    q += part[((size_t)i * 1024 + c) * 2 + 1];
  }
  float mu = s / 8192.f;
  float var = q / 8192.f - mu * mu;
  float sc = rsqrtf(var + 1e-5f) * gw[c];
  scale[c] = sc;
  shift[c] = bw[c] - mu * sc;
}

// BN apply + tanh, writes padded bf16 activations (pad rows -> 0)
__global__ void k_bn_tanh(const float* __restrict__ conv, const float* __restrict__ scale,
                          const float* __restrict__ shift, u16* __restrict__ outp) {
  int i = blockIdx.x * 256 + threadIdx.x;
  int c4 = i & 255;
  int prow = i >> 8;
  int b = prow / PTR, pt = prow % PTR;
  ushort4 o;
  if (pt < 2 || pt >= 1026) {
    o.x = 0; o.y = 0; o.z = 0; o.w = 0;
  } else {
    float4 v = ((const float4*)conv)[((size_t)(b * 1024 + pt - 2) << 8) + c4];
    int c = c4 * 4;
    o.x = f2bf(tanhf(v.x * scale[c + 0] + shift[c + 0]));
    o.y = f2bf(tanhf(v.y * scale[c + 1] + shift[c + 1]));
    o.z = f2bf(tanhf(v.z * scale[c + 2] + shift[c + 2]));
    o.w = f2bf(tanhf(v.w * scale[c + 3] + shift[c + 3]));
  }
  ((ushort4*)outp)[i] = o;
}

// zero the 4 pad rows per batch of p_concat
__global__ void k_zero_pads(u16* __restrict__ pcat) {
  int i = blockIdx.x * 256 + threadIdx.x;
  int c = i & 1023;
  int r = i >> 10;
  int b = r >> 2, q = r & 3;
  int pt = (q < 2) ? q : (1024 + q);
  pcat[((size_t)(b * PTR + pt) << 10) + c] = 0;
}

// ---------------- BiLSTM scan ----------------
// 32 WGs (16/dir) x 256 thr. WG w owns gate cols {g*512 + w*32 + j}. wh slice packed
// in MFMA-fragment order in LDS (128KB, loaded once, conflict-free ds_read_b128).
// Sync protocol: relaxed agent-scope atomics only (coherence-point ops; no acquire
// invalidates / release writebacks that would thrash L2). Ordering: __syncthreads()
// drains vmcnt(0) before the per-WG per-step flag store; flags live on separate
// cachelines per producer (no shared-counter RMW serialization).
__launch_bounds__(256)
__global__ void k_lstm(const u16* __restrict__ xgf, const u16* __restrict__ xgb,
                       const u16* __restrict__ whfT, const u16* __restrict__ whbT,
                       u16* __restrict__ pcat, u32* flags, u32* hbuf) {
  const int wg = blockIdx.x, dir = wg >> 4, w = wg & 15;
  const u16* xg = dir ? xgb : xgf;
  const u16* whT = dir ? whbT : whfT;
  __shared__ alignas(16) u16 whS[65536];      // 128KB: 128 blocks of 1KB (frag-packed)
  __shared__ alignas(16) u16 h_sl[16 * 512];  // XOR-swizzled rows; rows 8..15 stay zero
  __shared__ float g_sl[8 * 132];
  const int tid = threadIdx.x, lane = tid & 63, wv = tid >> 6;

  // pack wh slice into fragment order: block (wv*2+n)*16+kk holds the B-frag
  // (1KB, lane*16 layout) for col-tile n of wave wv at K-step kk.
#pragma unroll
  for (int n = 0; n < 2; ++n)
#pragma unroll
    for (int kk = 0; kk < 16; ++kk) {
      int gcol = wv * 512 + w * 32 + n * 16 + (lane & 15);
      const u16* src = whT + (size_t)gcol * 512 + kk * 32 + (lane >> 4) * 8;
      int blk = (wv * 2 + n) * 16 + kk;
      *(bf16x8*)((char*)whS + blk * 1024 + lane * 16) = *(const bf16x8*)src;
    }
  for (int i = tid; i < 4096; i += 256) ((u32*)h_sl)[i] = 0;
  __syncthreads();

  const int b = tid >> 5, jj = tid & 31;
  float c_reg = 0.f;
  const char* bbase = (const char*)whS + (wv * 32) * 1024 + lane * 16;

  for (int s = 0; s < 1024; ++s) {
    const int t = dir ? (1023 - s) : s;
    // prefetch xg for this step (independent of the wait)
    const u16* xr = xg + ((size_t)(b * 1024 + t)) * 2048 + w * 32 + jj;
    float xi = bf2f(xr[0]);
    float xf = bf2f(xr[512]);
    float xgg = bf2f(xr[1024]);
    float xo = bf2f(xr[1536]);

    if (s > 0) {
      if (wv == 0 && lane < 16) {
        const u32* fp = flags + ((size_t)(dir * 16 + lane)) * 1024 + (s - 1);
        while (__hip_atomic_load(fp, __ATOMIC_RELAXED, __HIP_MEMORY_SCOPE_AGENT) == 0) {}
      }
      __syncthreads();
      const u64* hb8 = (const u64*)(hbuf + (dir * 2 + ((s - 1) & 1)) * 2048);
#pragma unroll
      for (int i = 0; i < 4; ++i) {
        int idx = tid + 256 * i;            // u64 index, 1024 total = 8 rows x 128
        u64 v = __hip_atomic_load(&hb8[idx], __ATOMIC_RELAXED, __HIP_MEMORY_SCOPE_AGENT);
        int r = idx >> 7;
        int cb = (idx & 127) << 3;
        *(u64*)((char*)h_sl + r * 1024 + (cb ^ ((r & 7) << 4))) = v;
      }
      __syncthreads();
    }

    // recurrent GEMM: g_part[8 x 128] = h[8 x 512] @ wh_slice (2 col-tiles/wave)
    f32x4 acc0 = {0, 0, 0, 0}, acc1 = {0, 0, 0, 0};
#pragma unroll
    for (int kk = 0; kk < 16; ++kk) {
      int ar = lane & 15;
      int kb = kk * 64 + (lane >> 4) * 16;
      bf16x8 a = *(const bf16x8*)((const char*)h_sl + ar * 1024 + (kb ^ ((ar & 7) << 4)));
      bf16x8 b0 = *(const bf16x8*)(bbase + kk * 1024);
      bf16x8 b1 = *(const bf16x8*)(bbase + (16 + kk) * 1024);
      acc0 = __builtin_amdgcn_mfma_f32_16x16x32_bf16(a, b0, acc0, 0, 0, 0);
      acc1 = __builtin_amdgcn_mfma_f32_16x16x32_bf16(a, b1, acc1, 0, 0, 0);
    }
#pragma unroll
    for (int j = 0; j < 4; ++j) {
      int row = (lane >> 4) * 4 + j;
      if (row < 8) {
        g_sl[row * 132 + wv * 32 + (lane & 15)] = acc0[j];
        g_sl[row * 132 + wv * 32 + 16 + (lane & 15)] = acc1[j];
      }
    }
    __syncthreads();

    // gates: thread = (b, jj)
    {
      float gi = xi + g_sl[b * 132 + jj];
      float gf = xf + g_sl[b * 132 + 32 + jj];
      float gg = xgg + g_sl[b * 132 + 64 + jj];
      float go = xo + g_sl[b * 132 + 96 + jj];
      float si = 1.f / (1.f + __expf(-gi));
      float sf = 1.f / (1.f + __expf(-gf));
      float so = 1.f / (1.f + __expf(-go));
      gg = fminf(fmaxf(gg, -15.f), 15.f);
      float e2g = __expf(2.f * gg);
      float tg = (e2g - 1.f) / (e2g + 1.f);
      float cc = sf * c_reg + si * tg;
      c_reg = cc;
      float ccl = fminf(fmaxf(cc, -15.f), 15.f);
      float e2c = __expf(2.f * ccl);
      float th = (e2c - 1.f) / (e2c + 1.f);
      float hh = so * th;
      u16 hbits = f2bf(hh);
      pcat[((size_t)(b * PTR + t + 2) << 10) + dir * 512 + w * 32 + jj] = hbits;
      int other = __shfl_down((int)hbits, 1);
      if (!(jj & 1)) {
        u32 val = (u32)hbits | ((u32)(other & 0xffff) << 16);
        u32* hbo = hbuf + (dir * 2 + (s & 1)) * 2048;
        __hip_atomic_store(&hbo[b * 256 + w * 16 + (jj >> 1)], val, __ATOMIC_RELAXED,
                           __HIP_MEMORY_SCOPE_AGENT);
      }
    }
    __syncthreads();  // drains vmcnt(0): all hbuf stores complete at coherence point
    if (tid == 0)
      __hip_atomic_store(flags + ((size_t)(dir * 16 + w)) * 1024 + s, 1u,
                         __ATOMIC_RELAXED, __HIP_MEMORY_SCOPE_AGENT);
  }
}

// ---------------- host ----------------
extern "C" void kernel_launch(void* const* d_in, const int* in_sizes, int n_in,
                              void* d_out, int out_size, void* d_ws, size_t ws_size,
                              hipStream_t stream) {
  const float* x    = (const float*)d_in[0];
  const float* w1   = (const float*)d_in[1];
  const float* b1   = (const float*)d_in[2];
  const float* w2   = (const float*)d_in[3];
  const float* b2   = (const float*)d_in[4];
  const float* wx_f = (const float*)d_in[5];
  const float* wh_f = (const float*)d_in[6];
  const float* bl_f = (const float*)d_in[7];
  const float* wx_b = (const float*)d_in[8];
  const float* wh_b = (const float*)d_in[9];
  const float* bl_b = (const float*)d_in[10];
  const float* ck1  = (const float*)d_in[11];
  const float* cb1  = (const float*)d_in[12];
  const float* g1   = (const float*)d_in[13];
  const float* be1  = (const float*)d_in[14];
  const float* ck2  = (const float*)d_in[15];
  const float* cb2  = (const float*)d_in[16];
  const float* g2   = (const float*)d_in[17];
  const float* be2  = (const float*)d_in[18];
  const float* ck3  = (const float*)d_in[19];
  const float* cb3  = (const float*)d_in[20];
  float* out = (float*)d_out;

  char* ws = (char*)d_ws;
  size_t off = 0;
  auto alloc = [&](size_t n) { size_t o = off; off += (n + 255) & ~(size_t)255; return o; };
  u16* w1T  = (u16*)(ws + alloc((size_t)1024 * 1024 * 2));
  u16* w2T  = (u16*)(ws + alloc((size_t)1024 * 1024 * 2));
  u16* wxfT = (u16*)(ws + alloc((size_t)2048 * 1024 * 2));
  u16* wxbT = (u16*)(ws + alloc((size_t)2048 * 1024 * 2));
  u16* whfT = (u16*)(ws + alloc((size_t)2048 * 512 * 2));
  u16* whbT = (u16*)(ws + alloc((size_t)2048 * 512 * 2));
  u16* ck1T = (u16*)(ws + alloc((size_t)1024 * KCONV * 2));
  u16* ck2T = (u16*)(ws + alloc((size_t)1024 * KCONV * 2));
  u16* ck3T = (u16*)(ws + alloc((size_t)1024 * KCONV * 2));
  u16* xb   = (u16*)(ws + alloc((size_t)MR * 1024 * 2));
  u16* h1   = (u16*)(ws + alloc((size_t)MR * 1024 * 2));
  u16* hm   = (u16*)(ws + alloc((size_t)MR * 1024 * 2));
  u16* xgf  = (u16*)(ws + alloc((size_t)MR * 2048 * 2));
  u16* xgb  = (u16*)(ws + alloc((size_t)MR * 2048 * 2));
  u16* pcat = (u16*)(ws + alloc((size_t)BATCH * PTR * 1024 * 2));
  u16* pa1  = (u16*)(ws + alloc((size_t)BATCH * PTR * 1024 * 2));
  u16* pa2  = (u16*)(ws + alloc((size_t)BATCH * PTR * 1024 * 2));
  u32* hbuf = (u32*)(ws + alloc((size_t)2 * 2 * 2048 * 4));
  u32* flags = (u32*)(ws + alloc((size_t)2 * LNW * 1024 * 4));
  float* part  = (float*)(ws + alloc((size_t)64 * 1024 * 2 * 4));
  float* scale = (float*)(ws + alloc((size_t)1024 * 4));
  float* shift = (float*)(ws + alloc((size_t)1024 * 4));
  (void)ws_size; (void)in_sizes; (void)n_in; (void)out_size;

  dim3 tb(32, 8);
  // weight transposes + bf16 conversion
  k_transpose<<<dim3(32, 32), tb, 0, stream>>>(w1, w1T, 1024, 1024);
  k_transpose<<<dim3(32, 32), tb, 0, stream>>>(w2, w2T, 1024, 1024);
  k_transpose<<<dim3(64, 32), tb, 0, stream>>>(wx_f, wxfT, 1024, 2048);
  k_transpose<<<dim3(64, 32), tb, 0, stream>>>(wx_b, wxbT, 1024, 2048);
  k_transpose<<<dim3(64, 16), tb, 0, stream>>>(wh_f, whfT, 512, 2048);
  k_transpose<<<dim3(64, 16), tb, 0, stream>>>(wh_b, whbT, 512, 2048);
  k_transpose<<<dim3(32, 160), tb, 0, stream>>>(ck1, ck1T, KCONV, 1024);
  k_transpose<<<dim3(32, 160), tb, 0, stream>>>(ck2, ck2T, KCONV, 1024);
  k_transpose<<<dim3(32, 160), tb, 0, stream>>>(ck3, ck3T, KCONV, 1024);
  k_f32_to_bf16<<<8192, 256, 0, stream>>>(x, xb, MR * 1024 / 4);

  // MLP
  k_gemm<1><<<dim3(8, 64), 256, 0, stream>>>(xb, w1T, b1, h1, MR, 1024, 1024);
  k_gemm<0><<<dim3(8, 64), 256, 0, stream>>>(h1, w2T, b2, hm, MR, 1024, 1024);
  // LSTM input projections (bias folded in)
  k_gemm<0><<<dim3(16, 64), 256, 0, stream>>>(hm, wxfT, bl_f, xgf, MR, 2048, 1024);
  k_gemm<0><<<dim3(16, 64), 256, 0, stream>>>(hm, wxbT, bl_b, xgb, MR, 2048, 1024);

  // LSTM scan
  hipMemsetAsync(flags, 0, (size_t)2 * LNW * 1024 * 4, stream);
  k_zero_pads<<<128, 256, 0, stream>>>(pcat);
  k_lstm<<<32, 256, 0, stream>>>(xgf, xgb, whfT, whbT, pcat, flags, hbuf);

  // conv1 + BN + tanh
  k_conv_gemm<<<dim3(8, 64), 256, 0, stream>>>(pcat, ck1T, cb1, out);
  k_bnstats1<<<64, 256, 0, stream>>>(out, part);
  k_bnstats2<<<4, 256, 0, stream>>>(part, g1, be1, scale, shift);
  k_bn_tanh<<<8224, 256, 0, stream>>>(out, scale, shift, pa1);
  // conv2 + BN + tanh
  k_conv_gemm<<<dim3(8, 64), 256, 0, stream>>>(pa1, ck2T, cb2, out);
  k_bnstats1<<<64, 256, 0, stream>>>(out, part);
  k_bnstats2<<<4, 256, 0, stream>>>(part, g2, be2, scale, shift);
  k_bn_tanh<<<8224, 256, 0, stream>>>(out, scale, shift, pa2);
  // conv3 (final, fp32 out)
  k_conv_gemm<<<dim3(8, 64), 256, 0, stream>>>(pa2, ck3T, cb3, out);
}